// Round 7
// baseline (158.400 us; speedup 1.0000x reference)
//
#include <hip/hip_runtime.h>
#include <math.h>

#define N_NODES 2048
#define NB 256  // 256 blocks = 256 CUs, 1 block/CU, co-resident

__device__ __forceinline__ float invdeg(int j) { return j > 0 ? 1.0f / (float)j : 0.0f; }

// Publish: group stores -> __syncthreads -> single-thread agent release fence +
// relaxed flag store. Consume: per-thread relaxed poll -> __syncthreads ->
// agent acquire fence (all threads) -> read data. Same fence pattern that
// validated correct in R5/R6; here it is fine-grained per tile, never grid-wide.
__device__ __forceinline__ void publish(int* flag) {
  __syncthreads();
  if (threadIdx.x == 0) {
    __builtin_amdgcn_fence(__ATOMIC_RELEASE, "agent");
    __hip_atomic_store(flag, 1, __ATOMIC_RELAXED, __HIP_MEMORY_SCOPE_AGENT);
  }
}
__device__ __forceinline__ void poll1(int* flag) {
  while (__hip_atomic_load(flag, __ATOMIC_RELAXED, __HIP_MEMORY_SCOPE_AGENT) == 0)
    __builtin_amdgcn_s_sleep(4);
}

__global__ __launch_bounds__(256) void k_pipe(
    const float* __restrict__ x, const float* __restrict__ cent,
    const float* __restrict__ Ws1, const float* __restrict__ Wn1,
    const float* __restrict__ b1, const float* __restrict__ Ws2,
    const float* __restrict__ Wn2, const float* __restrict__ b2,
    const float* __restrict__ Wm1, const float* __restrict__ bm1,
    const float* __restrict__ Wm2, const float* __restrict__ bm2,
    int* flag1, int* flag2, int* flagAB,
    float* agg1, float* agg2, float* A, float* Bm,
    float2* __restrict__ out) {
  __shared__ float cs[N_NODES * 3];  // 24 KB centroid stage
  __shared__ float Xs[8][32], XSQ[8][32];
  __shared__ float invn_l[8];
  __shared__ float cd[8][3];
  __shared__ float n1t[8][36];
  __shared__ float h1t[8][64];
  __shared__ float n2t[8][64];
  __shared__ float h2t[8][32];
  __shared__ float part[8][64];
  __shared__ float Pre[64];

  const int tid = threadIdx.x;
  const int b = blockIdx.x;      // tile index: nodes [8b, 8b+8)
  const int base = b * 8;
  const int wv = tid >> 6, lane = tid & 63;

  // ---- S1: x-tile load, inv-norms, x^2*invn, tile aggregate (no deps) ----
  {
    const int n = tid >> 5, f = tid & 31;
    float xv = x[(base + n) * 32 + f];
    float sq = xv * xv;
    float s = sq;
#pragma unroll
    for (int d = 16; d > 0; d >>= 1) s += __shfl_xor(s, d, 32);
    float invn = rsqrtf(s);
    Xs[n][f] = xv;
    XSQ[n][f] = sq * invn;
    if (f == 0) invn_l[n] = invn;
    // stage centroids (coalesced float4)
    const float4* cp = (const float4*)cent;
    float4* csp = (float4*)cs;
#pragma unroll
    for (int q = 0; q < 6; ++q) csp[tid + 256 * q] = cp[tid + 256 * q];
  }
  __syncthreads();
  if (tid < 32) {
    float s = 0.f;
#pragma unroll
    for (int n = 0; n < 8; ++n) s += XSQ[n][tid];
    agg1[b * 32 + tid] = s;
  }
  publish(&flag1[b * 16]);

  // ---- S2: centroid |diff| sums for own 8 nodes (no deps, overlaps others) ----
#pragma unroll
  for (int r = 0; r < 2; ++r) {
    const int n = wv + 4 * r;
    const int gn = base + n;
    const float c0 = cs[gn * 3], c1 = cs[gn * 3 + 1], c2 = cs[gn * 3 + 2];
    float s0 = 0.f, s1 = 0.f, s2 = 0.f;
    for (int i = lane; i < gn; i += 64) {
      float a0 = cs[i * 3], a1 = cs[i * 3 + 1], a2 = cs[i * 3 + 2];
      s0 += a0 * fabsf(a0 - c0);
      s1 += a1 * fabsf(a1 - c1);
      s2 += a2 * fabsf(a2 - c2);
    }
#pragma unroll
    for (int d = 32; d > 0; d >>= 1) {
      s0 += __shfl_down(s0, d);
      s1 += __shfl_down(s1, d);
      s2 += __shfl_down(s2, d);
    }
    if (lane == 0) {
      float g = invdeg(gn);
      cd[n][0] = s0 * g; cd[n][1] = s1 * g; cd[n][2] = s2 * g;
    }
  }

  // ---- S3: lookback over agg1 -> Pre[f] (exclusive prefix of x^2*invn) ----
  if (tid < b) poll1(&flag1[tid * 16]);
  __syncthreads();
  __builtin_amdgcn_fence(__ATOMIC_ACQUIRE, "agent");
  {
    const int f = tid & 31, c = tid >> 5;  // 8 chunks
    float s = 0.f;
    for (int p = c; p < b; p += 8) s += agg1[p * 32 + f];
    part[c][f] = s;
  }
  __syncthreads();
  if (tid < 32) {
    float s = 0.f;
#pragma unroll
    for (int c2 = 0; c2 < 8; ++c2) s += part[c2][tid];
    Pre[tid] = s;
  }
  __syncthreads();

  // ---- S4: n1 tile, h1 tile, publish h1 row-sum aggregate ----
  {
    const int n = tid >> 5, f = tid & 31;
    const int gn = base + n;
    float pre = Pre[f];
    for (int m = 0; m < n; ++m) pre += XSQ[m][f];
    n1t[n][f] = pre * Xs[n][f] * invn_l[n] * invdeg(gn);
    if (f < 3) n1t[n][32 + f] = cd[n][f];
  }
  __syncthreads();
  {
    const int o = tid & 63, nh = tid >> 6;  // handles nodes nh and nh+4
    float acc0 = b1[o], acc1 = b1[o];
#pragma unroll
    for (int f = 0; f < 32; ++f) {
      float ws = Ws1[f * 64 + o], wn = Wn1[f * 64 + o];
      acc0 += Xs[nh][f] * ws + n1t[nh][f] * wn;
      acc1 += Xs[nh + 4][f] * ws + n1t[nh + 4][f] * wn;
    }
#pragma unroll
    for (int f = 32; f < 35; ++f) {
      float ws = Ws1[f * 64 + o], wn = Wn1[f * 64 + o];
      acc0 += cs[(base + nh) * 3 + (f - 32)] * ws + n1t[nh][f] * wn;
      acc1 += cs[(base + nh + 4) * 3 + (f - 32)] * ws + n1t[nh + 4][f] * wn;
    }
    h1t[nh][o] = acc0;
    h1t[nh + 4][o] = acc1;
  }
  __syncthreads();
  if (tid < 64) {
    float s = 0.f;
#pragma unroll
    for (int n = 0; n < 8; ++n) s += h1t[n][tid];
    agg2[b * 64 + tid] = s;
  }
  publish(&flag2[b * 16]);

  // ---- S5: lookback over agg2 -> Pre[o] (exclusive prefix of h1 rows) ----
  if (tid < b) poll1(&flag2[tid * 16]);
  __syncthreads();
  __builtin_amdgcn_fence(__ATOMIC_ACQUIRE, "agent");
  {
    const int o = tid & 63, c = tid >> 6;  // 4 chunks
    float s = 0.f;
    for (int p = c; p < b; p += 4) s += agg2[p * 64 + o];
    part[c][o] = s;
  }
  __syncthreads();
  if (tid < 64) {
    float s = 0.f;
#pragma unroll
    for (int c2 = 0; c2 < 4; ++c2) s += part[c2][tid];
    Pre[tid] = s;
  }
  __syncthreads();

  // ---- S6: n2 tile, h2 tile, A/B rows, publish tile-ready flag ----
  {
    const int o = tid & 63, nh = tid >> 6;
#pragma unroll
    for (int r = 0; r < 2; ++r) {
      const int n = nh + 4 * r;
      float s = Pre[o];
      for (int m = 0; m < n; ++m) s += h1t[m][o];
      n2t[n][o] = s * invdeg(base + n);
    }
  }
  __syncthreads();
  {
    const int g = tid & 31, n = tid >> 5;
    float acc = b2[g];
#pragma unroll
    for (int f = 0; f < 64; ++f)
      acc += h1t[n][f] * Ws2[f * 32 + g] + n2t[n][f] * Wn2[f * 32 + g];
    h2t[n][g] = acc;
  }
  __syncthreads();
  {
    const int g = tid & 31, n = tid >> 5;
    float a = 0.f, bb = bm1[g];
#pragma unroll
    for (int f = 0; f < 32; ++f) {
      float v = h2t[n][f];
      a += v * Wm1[f * 32 + g];
      bb += v * Wm1[(32 + f) * 32 + g];
    }
    A[(base + n) * 32 + g] = a;
    Bm[(base + n) * 32 + g] = bb;
  }
  publish(&flagAB[b * 16]);

  // ---- S7: edge chunks (8 i-rows x 256 j-cols), poll only needed tiles ----
  {
    float wd[32];
#pragma unroll
    for (int f = 0; f < 32; ++f) wd[f] = Wm2[f * 2 + 1] - Wm2[f * 2];
    const float db = bm2[1] - bm2[0];
    for (int c = b; c < 1152; c += NB) {
      int jt = 0;
#pragma unroll
      for (int t = 1; t < 8; ++t)
        if (c >= 16 * t * (t + 1)) jt = t;
      const int ic = c - 16 * jt * (jt + 1);
      const int j0 = jt * 256;
      const int i0 = ic * 8;
      // wait on the 32 B-tiles + 1 A-tile this chunk reads
      if (tid < 32)
        poll1(&flagAB[((j0 >> 3) + tid) * 16]);
      else if (tid == 32)
        poll1(&flagAB[(i0 >> 3) * 16]);
      __syncthreads();
      __builtin_amdgcn_fence(__ATOMIC_ACQUIRE, "agent");
      const int j = j0 + tid;
      float Br[32];
      const float4* bp = (const float4*)(Bm + j * 32);
#pragma unroll
      for (int q = 0; q < 8; ++q) {
        float4 v = bp[q];
        Br[4 * q] = v.x; Br[4 * q + 1] = v.y;
        Br[4 * q + 2] = v.z; Br[4 * q + 3] = v.w;
      }
#pragma unroll
      for (int ii = 0; ii < 8; ++ii) {
        const int i = i0 + ii;
        const float* Ar = A + i * 32;  // wave-uniform row -> scalar loads
        float d = db;
#pragma unroll
        for (int f = 0; f < 32; ++f)
          d += fmaxf(Ar[f] + Br[f], 0.f) * wd[f];
        if (i < j) {
          float p0 = 1.0f / (1.0f + __expf(d));
          int e = i * (2 * N_NODES - 1 - i) / 2 + (j - i - 1);
          out[e] = make_float2(p0, 1.0f - p0);
        }
      }
    }
  }
}

extern "C" void kernel_launch(void* const* d_in, const int* in_sizes, int n_in,
                              void* d_out, int out_size, void* d_ws, size_t ws_size,
                              hipStream_t stream) {
  const float* x    = (const float*)d_in[0];
  const float* cent = (const float*)d_in[1];
  const float* Ws1  = (const float*)d_in[2];
  const float* Wn1  = (const float*)d_in[3];
  const float* b1   = (const float*)d_in[4];
  const float* Ws2  = (const float*)d_in[5];
  const float* Wn2  = (const float*)d_in[6];
  const float* b2   = (const float*)d_in[7];
  const float* Wm1  = (const float*)d_in[8];
  const float* bm1  = (const float*)d_in[9];
  const float* Wm2  = (const float*)d_in[10];
  const float* bm2  = (const float*)d_in[11];

  // ws layout: 3 flag arrays (256 flags each, 64B-spaced) then data
  int* flag1  = (int*)d_ws;            // 16 KB
  int* flag2  = flag1 + 4096;          // 16 KB
  int* flagAB = flag2 + 4096;          // 16 KB
  float* agg1 = (float*)(flagAB + 4096);  // 256*32
  float* agg2 = agg1 + 256 * 32;          // 256*64
  float* A    = agg2 + 256 * 64;          // 2048*32
  float* Bm   = A + 2048 * 32;            // 2048*32

  hipMemsetAsync(d_ws, 0, 49152, stream);  // zero the three flag arrays only
  k_pipe<<<NB, 256, 0, stream>>>(x, cent, Ws1, Wn1, b1, Ws2, Wn2, b2,
                                 Wm1, bm1, Wm2, bm2,
                                 flag1, flag2, flagAB, agg1, agg2, A, Bm,
                                 (float2*)d_out);
}